// Round 6
// baseline (401.410 us; speedup 1.0000x reference)
//
#include <hip/hip_runtime.h>
#include <hip/hip_cooperative_groups.h>
#include <math.h>

namespace cg = cooperative_groups;

#define VIF_EPS       1e-10f
#define SIGMA_NSQ     2.0f
#define SIGMA_MAX_INV (4.0f / (255.0f * 255.0f))
#define GAIN_LIMIT    100.0f

typedef float v2f __attribute__((ext_vector_type(2)));
typedef float v4f __attribute__((ext_vector_type(4)));

static __device__ __forceinline__ v2f splat2(float s) {
    v2f v; v.x = s; v.y = s; return v;
}

// jnp.pad mode='reflect' (no edge duplication). Overshoot < dim, single reflection suffices.
__device__ __forceinline__ int reflect_idx(int i, int n) {
    i = (i < 0) ? -i : i;
    i = (i >= n) ? (2 * n - 2 - i) : i;
    return i;
}

// Reference: sigma=N/5; g=exp(-x^2/(2 sigma^2)); win=outer(g,g)/sum -> separable gn = g/sum(g).
// R9: computed once into workspace (same device float ops -> bit-identical weights).
template <int N>
__device__ __forceinline__ void fill_weights_global(float* gw) {
    const float sigma = (float)N / 5.0f;
    const float denom = 2.0f * sigma * sigma;
    float tmp[N];
    float s = 0.0f;
    for (int i = 0; i < N; ++i) {
        float x = (float)i - (float)(N - 1) * 0.5f;
        float g = expf(-(x * x) / denom);
        tmp[i] = g;
        s += g;
    }
    for (int i = 0; i < N; ++i) gw[i] = tmp[i] / s;
}

// R7: 256-column tile. Output tile width (multiple of 4). 1920 = 8*240 exact.
constexpr int tile_w(int N) { return (256 - (N - 1)) & ~3; }

// ---- problem geometry (fixed shapes -> compile-time constants device-side) ----
constexpr int BATCH = 4;
constexpr int H0 = 1080, W0 = 1920;
constexpr int H1 = 540,  W1 = 960;
constexpr int H2 = 270,  W2 = 480;
constexpr int H3 = 135,  W3 = 240;

constexpr int cdiv(int a, int b) { return (a + b - 1) / b; }
constexpr int SX0 = cdiv(W0, tile_w(17)), SY0 = cdiv(H0, 8), N0 = SX0 * SY0;   // 8*135=1080
constexpr int SX1 = cdiv(W1, tile_w(9)),  SY1 = cdiv(H1, 8), N1 = SX1 * SY1;   // 4*68=272
constexpr int SX2 = cdiv(W2, tile_w(5)),  SY2 = cdiv(H2, 8), N2 = SX2 * SY2;   // 2*34=68
constexpr int SX3 = cdiv(W3, tile_w(3)),  SY3 = cdiv(H3, 8), N3 = SX3 * SY3;   // 1*17=17
constexpr int DGX1 = W1 / 120, ND1 = DGX1 * cdiv(H1, 8);    // 8*68=544
constexpr int DGX2 = W2 / 120, ND2 = DGX2 * cdiv(H2, 8);    // 4*34=136
constexpr int DGX3 = W3 / 120, ND3 = DGX3 * cdiv(H3, 8);    // 2*17=34

// ---- static shared layouts ----
// R8: EXACT-FIT 40960 B = 4 blocks/CU in 160 KiB exactly.
template <int N>
struct alignas(16) StatsSmem {
    v2f   a[8][256];    // (conv r, conv d)           16384 B
    v2f   bq[8][256];   // (conv r^2, conv d^2)       16384 B
    float c[8][256];    // conv rd                     8192 B
};                      // total 40960 B exactly
template <int N>
struct alignas(16) DownSmem {
    v2f vb[8][252];
};

// ---------------- stats body (vertical-first separable VIF) ----------------
// R10: trailing __syncthreads added -- body now runs inside a persistent-block
// loop, so next iteration's phase-1 LDS writes must not race this iteration's
// rsum-overlay reads.
template <int N>
__device__ __forceinline__ void stats_body(
    StatsSmem<N>& sm, const float* __restrict__ refp, const float* __restrict__ distp,
    const float* __restrict__ gw,
    int h, int w, float shift, double2* __restrict__ partial,
    int sy, int sx, int bx, int b) {
    constexpr int P   = (N - 1) / 2;
    constexpr int TW  = tile_w(N);
    constexpr int TH  = 8;
    constexpr int LR  = TH + 2 * P;      // rows loaded per column (halo minimum)
    constexpr int XG4 = TW / 4;          // 4-output x-groups per row
    constexpr int NT  = TH * XG4;        // phase-2 tasks (<= 504)
    constexpr int REPS = (NT + 255) / 256;

    const int tid = threadIdx.x;
    const int ytile = bx % sy;
    const int xtile = bx / sy;
    const int x0 = xtile * TW;
    const int y0 = ytile * TH;

    float wr[N];
#pragma unroll
    for (int j = 0; j < N; ++j) wr[j] = gw[j];   // uniform -> s_load, stays SGPR

    // ---- Phase 1: vertical conv from global (1 column/thread, 8 outputs) ----
    {
        const int cc = tid;                       // column 0..255
        const int gx = reflect_idx(x0 + cc - P, w);
        const float* rbase = refp  + (size_t)b * h * w;   // uniform -> SGPR base
        const float* dbase = distp + (size_t)b * h * w;

        v2f accA[TH], accB[TH];
        float accC[TH];
#pragma unroll
        for (int t = 0; t < TH; ++t) {
            accA[t] = splat2(0.f);
            accB[t] = splat2(0.f);
            accC[t] = 0.f;
        }

        auto acc_push = [&](int i, float r, float d) {
            v2f rd; rd.x = r; rd.y = d;
            v2f sq = rd * rd;          // v_pk_mul_f32: (r^2, d^2)
            float x = r * d;
#pragma unroll
            for (int t = 0; t < TH; ++t) {
                const int j = i - t;               // j-ascending per output t
                if (j >= 0 && j < N) {
                    const float wj = wr[j];
                    accA[t] += splat2(wj) * rd;    // v_pk_fma_f32
                    accB[t] += splat2(wj) * sq;
                    accC[t] += wj * x;
                }
            }
        };

        const int rowlo = y0 - P;
        if (rowlo >= 0 && rowlo + LR <= h) {
            // Interior fast path: shared 32-bit byte offset, uniform bases.
            unsigned voff = (unsigned)(rowlo * w + gx) * 4u;
            const unsigned vstep = (unsigned)w * 4u;
#pragma unroll
            for (int i = 0; i < LR; ++i) {
                float r = *(const float*)((const char*)rbase + voff) - shift;
                float d = *(const float*)((const char*)dbase + voff) - shift;
                voff += vstep;
                acc_push(i, r, d);
            }
        } else {
#pragma unroll
            for (int i = 0; i < LR; ++i) {
                const int gy = reflect_idx(rowlo + i, h);
                const size_t o = (size_t)gy * w + gx;
                float r = rbase[o] - shift;
                float d = dbase[o] - shift;
                acc_push(i, r, d);
            }
        }
#pragma unroll
        for (int t = 0; t < TH; ++t) {
            sm.a[t][cc]  = accA[t];   // ds_write_b64, compile-time row offsets
            sm.bq[t][cc] = accB[t];
            sm.c[t][cc]  = accC[t];
        }
    }
    __syncthreads();

    // ---- Phase 2: horizontal conv + VIF math (4 outputs/task, REPS task reps) ----
    float num_v = 0.f, den_v = 0.f;
    {
        constexpr int WC  = N + 3;         // window columns (even: N odd)
        constexpr int F4C = (WC + 3) / 4;
#pragma unroll
        for (int rep = 0; rep < REPS; ++rep) {
            const int task = tid + 256 * rep;
            if (task < NT) {
                const int row = task / XG4;
                const int xg  = task - row * XG4;

                v2f muA[4], muB[4];
                float muC[4];
#pragma unroll
                for (int q = 0; q < 4; ++q) {
                    muA[q] = splat2(0.f);
                    muB[q] = splat2(0.f);
                    muC[q] = 0.f;
                }

                const v4f* A4 = (const v4f*)&sm.a[row][xg * 4];
                const v4f* B4 = (const v4f*)&sm.bq[row][xg * 4];
#pragma unroll
                for (int f = 0; f < WC / 2; ++f) {
                    v4f ta = A4[f];
                    v4f tb = B4[f];
#pragma unroll
                    for (int hlf = 0; hlf < 2; ++hlf) {
                        const int k = 2 * f + hlf;
                        v2f pa = hlf ? __builtin_shufflevector(ta, ta, 2, 3)
                                     : __builtin_shufflevector(ta, ta, 0, 1);
                        v2f pb = hlf ? __builtin_shufflevector(tb, tb, 2, 3)
                                     : __builtin_shufflevector(tb, tb, 0, 1);
#pragma unroll
                        for (int q = 0; q < 4; ++q) {
                            const int j = k - q;  // j-ascending per output
                            if (j >= 0 && j < N) {
                                const float wj = wr[j];
                                muA[q] += splat2(wj) * pa;
                                muB[q] += splat2(wj) * pb;
                            }
                        }
                    }
                }
                // Scalar rd plane.
                {
                    const v4f* C4 = (const v4f*)&sm.c[row][xg * 4];
#pragma unroll
                    for (int f = 0; f < F4C; ++f) {
                        v4f t = C4[f];
#pragma unroll
                        for (int e = 0; e < 4; ++e) {
                            const int k = 4 * f + e;
                            const float x = (e == 0) ? t.x : (e == 1) ? t.y
                                          : (e == 2) ? t.z : t.w;
#pragma unroll
                            for (int q = 0; q < 4; ++q) {
                                const int j = k - q;
                                if (j >= 0 && j < N) muC[q] += wr[j] * x;
                            }
                        }
                    }
                }

                const int gy = y0 + row;
#pragma unroll
                for (int q = 0; q < 4; ++q) {
                    int gx = x0 + xg * 4 + q;
                    if (gx < w && gy < h) {
                        float mu1 = muA[q].x, mu2 = muA[q].y;
                        float s1  = fmaxf(0.f, muB[q].x - mu1 * mu1);
                        float s2  = fmaxf(0.f, muB[q].y - mu2 * mu2);
                        float s12 = muC[q] - mu1 * mu2;

                        float g  = s12 / (s1 + VIF_EPS);
                        float sv = s2 - g * s12;
                        if (s1 < VIF_EPS) { g = 0.f; sv = s2; s1 = 0.f; }
                        if (s2 < VIF_EPS) { g = 0.f; sv = 0.f; }
                        if (g  < 0.f)     { sv = s2; g = 0.f; }
                        if (sv <= VIF_EPS) sv = VIF_EPS;
                        g = fminf(g, GAIN_LIMIT);

                        float num_ar = __log2f(1.f + g * g * s1 / (sv + SIGMA_NSQ));
                        float den_ar = __log2f(1.f + s1 / SIGMA_NSQ);
                        if (s12 < 0.f) num_ar = 0.f;
                        if (s1 < SIGMA_NSQ) { num_ar = 1.f - s2 * SIGMA_MAX_INV; den_ar = 1.f; }
                        num_v += num_ar;
                        den_v += den_ar;
                    }
                }
            }
        }
    }

    // Block reduction. rsum overlaid on the a-plane.
#pragma unroll
    for (int off = 32; off > 0; off >>= 1) {
        num_v += __shfl_down(num_v, off);
        den_v += __shfl_down(den_v, off);
    }
    __syncthreads();                      // phase-2 LDS reads complete
    float* rs = reinterpret_cast<float*>(&sm);
    const int wid = tid >> 6, lane = tid & 63;
    if (lane == 0) { rs[wid] = num_v; rs[4 + wid] = den_v; }
    __syncthreads();
    if (tid == 0) {
        float ns = rs[0] + rs[1] + rs[2] + rs[3];
        float ds = rs[4] + rs[5] + rs[6] + rs[7];
        partial[(size_t)b * (sy * sx) + bx] = make_double2((double)ns, (double)ds);
    }
    __syncthreads();                      // R10: protect rs reads from next-iter writes
}

// ---------------- downsample body: vertical-first, 120x8 output tile ----------------
template <int N>
__device__ __forceinline__ void down_body(
    DownSmem<N>& sm, const float* __restrict__ rin, const float* __restrict__ din,
    const float* __restrict__ gw,
    float* __restrict__ rout, float* __restrict__ dout,
    int h, int w, int h2, int w2, float shift, int dgx, int bx, int b) {
    constexpr int P   = (N - 1) / 2;
    constexpr int TOW = 120, TOH = 8;
    constexpr int IC  = 2 * (TOW - 1) + N;   // input cols needed (<= 247)
    constexpr int NR  = 2 * (TOH - 1) + N;   // input rows needed (14+N)
    constexpr int XG4 = TOW / 4;             // 30 x-groups (4 outputs each)
    constexpr int WL  = N + 6;               // window v2f cols for 4 outputs

    float wr[N];
#pragma unroll
    for (int j = 0; j < N; ++j) wr[j] = gw[j];   // uniform -> s_load

    const int tid = threadIdx.x;
    const int xt  = bx % dgx;
    const int yt  = bx / dgx;
    const int x0  = xt * TOW;
    const int y0  = yt * TOH;

    // ---- Vertical decimating pass (packed, streaming) ----
    if (tid < IC) {
        const int gx = reflect_idx(2 * x0 - P + tid, w);
        const int rowlo = 2 * y0 - P;
        const float* rbase = rin + (size_t)b * h * w;
        const float* dbase = din + (size_t)b * h * w;

        v2f acc[TOH];
#pragma unroll
        for (int t = 0; t < TOH; ++t) acc[t] = splat2(0.f);

        const bool interior = (rowlo >= 0) && (rowlo + NR <= h);
        if (interior) {
            unsigned voff = (unsigned)(rowlo * w + gx) * 4u;
            const unsigned vstep = (unsigned)w * 4u;
#pragma unroll
            for (int i = 0; i < NR; ++i) {
                v2f x;
                x.x = *(const float*)((const char*)rbase + voff) - shift;
                x.y = *(const float*)((const char*)dbase + voff) - shift;
                voff += vstep;
#pragma unroll
                for (int t = 0; t < TOH; ++t) {
                    const int j = i - 2 * t;
                    if (j >= 0 && j < N) acc[t] += splat2(wr[j]) * x;
                }
            }
        } else {
#pragma unroll
            for (int i = 0; i < NR; ++i) {
                const int gy = reflect_idx(rowlo + i, h);
                const size_t o = (size_t)gy * w + gx;
                v2f x; x.x = rbase[o] - shift; x.y = dbase[o] - shift;
#pragma unroll
                for (int t = 0; t < TOH; ++t) {
                    const int j = i - 2 * t;
                    if (j >= 0 && j < N) acc[t] += splat2(wr[j]) * x;
                }
            }
        }
#pragma unroll
        for (int t = 0; t < TOH; ++t) sm.vb[t][tid] = acc[t];   // ds_write_b64
    }
    __syncthreads();

    // ---- Horizontal decimating pass (packed) ----
    if (tid < TOH * XG4) {   // 240 threads
        const int row = tid / XG4;
        const int xg  = tid - row * XG4;

        v2f o[4];
#pragma unroll
        for (int q = 0; q < 4; ++q) o[q] = splat2(0.f);

        const v4f* s4 = (const v4f*)&sm.vb[row][8 * xg];
#pragma unroll
        for (int f = 0; f < (WL + 1) / 2; ++f) {
            v4f t = s4[f];
#pragma unroll
            for (int hlf = 0; hlf < 2; ++hlf) {
                const int k = 2 * f + hlf;
                v2f p = hlf ? __builtin_shufflevector(t, t, 2, 3)
                            : __builtin_shufflevector(t, t, 0, 1);
#pragma unroll
                for (int q = 0; q < 4; ++q) {
                    const int j = k - 2 * q;   // j-ascending per output: bit-identical
                    if (j >= 0 && j < N) o[q] += splat2(wr[j]) * p;
                }
            }
        }
        const int gy = y0 + row;
        if (gy < h2) {
            float* rp = rout + (size_t)b * h2 * w2 + (size_t)gy * w2 + x0 + 4 * xg;
            float* dp = dout + (size_t)b * h2 * w2 + (size_t)gy * w2 + x0 + 4 * xg;
            *(float4*)rp = make_float4(o[0].x, o[1].x, o[2].x, o[3].x);
            *(float4*)dp = make_float4(o[0].y, o[1].y, o[2].y, o[3].y);
        }
    }
    __syncthreads();          // R10: protect vb reads from next-iter vertical writes
}

// ---------------- R10: one cooperative persistent-block mega-kernel ----------------
// total-K1 was pinned at ~100 us across R0..R5 while K1 fell 118->70: the residue
// is 6 serial launch boundaries (~13 us each), not K2-K5 exec (~20 us by work).
// One launch, NB co-resident blocks, grid.sync() between levels. Per-tile
// computation and partial writes identical -> bit-identical output.
struct MegaParams {
    const float* ref; const float* dist;
    float* gw;
    float* ref1; float* dist1; float* ref2; float* dist2; float* ref3; float* dist3;
    double2 *p0, *p1, *p2, *p3;
    float* out;
};

__global__ __launch_bounds__(256) void mega_kernel(MegaParams P) {
    __shared__ union {
        StatsSmem<17> s17; StatsSmem<9> s9; StatsSmem<5> s5; StatsSmem<3> s3;
        DownSmem<9> d9; DownSmem<5> d5; DownSmem<3> d3;
        struct { double sn[4], sd[4]; } red;
    } u;
    cg::grid_group grid = cg::this_grid();
    const int nb  = gridDim.x;
    const int bid = blockIdx.x;
    const int tid = threadIdx.x;

    // phase 0: weight table (once; bit-identical device float ops)
    if (bid == 0) {
        if (tid == 0)      fill_weights_global<17>(P.gw + 0);
        else if (tid == 1) fill_weights_global<9>(P.gw + 17);
        else if (tid == 2) fill_weights_global<5>(P.gw + 26);
        else if (tid == 3) fill_weights_global<3>(P.gw + 31);
        __threadfence();
    }
    grid.sync();

    // level 0: stats<17> + down<9>
    for (int v = bid; v < (N0 + ND1) * BATCH; v += nb) {
        const int b = v / (N0 + ND1), bx = v % (N0 + ND1);
        if (bx < N0)
            stats_body<17>(u.s17, P.ref, P.dist, P.gw + 0, H0, W0, 128.f,
                           P.p0, SY0, SX0, bx, b);
        else
            down_body<9>(u.d9, P.ref, P.dist, P.gw + 17, P.ref1, P.dist1,
                         H0, W0, H1, W1, 128.f, DGX1, bx - N0, b);
    }
    grid.sync();

    // level 1: stats<9> + down<5>
    for (int v = bid; v < (N1 + ND2) * BATCH; v += nb) {
        const int b = v / (N1 + ND2), bx = v % (N1 + ND2);
        if (bx < N1)
            stats_body<9>(u.s9, P.ref1, P.dist1, P.gw + 17, H1, W1, 0.f,
                          P.p1, SY1, SX1, bx, b);
        else
            down_body<5>(u.d5, P.ref1, P.dist1, P.gw + 26, P.ref2, P.dist2,
                         H1, W1, H2, W2, 0.f, DGX2, bx - N1, b);
    }
    grid.sync();

    // level 2: stats<5> + down<3>
    for (int v = bid; v < (N2 + ND3) * BATCH; v += nb) {
        const int b = v / (N2 + ND3), bx = v % (N2 + ND3);
        if (bx < N2)
            stats_body<5>(u.s5, P.ref2, P.dist2, P.gw + 26, H2, W2, 0.f,
                          P.p2, SY2, SX2, bx, b);
        else
            down_body<3>(u.d3, P.ref2, P.dist2, P.gw + 31, P.ref3, P.dist3,
                         H2, W2, H3, W3, 0.f, DGX3, bx - N2, b);
    }
    grid.sync();

    // level 3: stats<3>
    for (int v = bid; v < N3 * BATCH; v += nb) {
        const int b = v / N3, bx = v % N3;
        stats_body<3>(u.s3, P.ref3, P.dist3, P.gw + 31, H3, W3, 0.f,
                      P.p3, SY3, SX3, bx, b);
    }
    grid.sync();

    // reduce: 16 virtual blocks, one per (batch, scale)
    for (int v = bid; v < 4 * BATCH; v += nb) {
        const int s = v & 3;
        const int b = v >> 2;
        const double2* p; int cnt;
        if (s == 0)      { p = P.p0; cnt = N0; }
        else if (s == 1) { p = P.p1; cnt = N1; }
        else if (s == 2) { p = P.p2; cnt = N2; }
        else             { p = P.p3; cnt = N3; }
        p += (size_t)b * cnt;

        double ns = 0.0, ds = 0.0;
        for (int i = tid; i < cnt; i += 256) {
            double2 t = p[i];
            ns += t.x;
            ds += t.y;
        }
#pragma unroll
        for (int off = 32; off > 0; off >>= 1) {
            ns += __shfl_down(ns, off);
            ds += __shfl_down(ds, off);
        }
        const int wid = tid >> 6, lane = tid & 63;
        if (lane == 0) { u.red.sn[wid] = ns; u.red.sd[wid] = ds; }
        __syncthreads();
        if (tid == 0) {
            double Nv = u.red.sn[0] + u.red.sn[1] + u.red.sn[2] + u.red.sn[3];
            double Dv = u.red.sd[0] + u.red.sd[1] + u.red.sd[2] + u.red.sd[3];
            P.out[b * 4 + s] = (float)(Nv / Dv);
        }
        __syncthreads();
    }
}

extern "C" void kernel_launch(void* const* d_in, const int* in_sizes, int n_in,
                              void* d_out, int out_size, void* d_ws, size_t ws_size,
                              hipStream_t stream) {
    const float* ref  = (const float*)d_in[0];
    const float* dist = (const float*)d_in[1];
    float* out = (float*)d_out;

    char*  ws  = (char*)d_ws;
    size_t off = 0;
    auto alloc = [&](size_t bytes) -> void* {
        void* p = ws + off;
        off += (bytes + 255) & ~(size_t)255;
        return p;
    };
    float* gw    = (float*)alloc(34 * sizeof(float));   // weight table (17+9+5+3)
    float* ref1  = (float*)alloc((size_t)BATCH * H1 * W1 * 4);
    float* dist1 = (float*)alloc((size_t)BATCH * H1 * W1 * 4);
    float* ref2  = (float*)alloc((size_t)BATCH * H2 * W2 * 4);
    float* dist2 = (float*)alloc((size_t)BATCH * H2 * W2 * 4);
    float* ref3  = (float*)alloc((size_t)BATCH * H3 * W3 * 4);
    float* dist3 = (float*)alloc((size_t)BATCH * H3 * W3 * 4);

    double2* part = (double2*)alloc((size_t)BATCH * (N0 + N1 + N2 + N3) * sizeof(double2));
    double2* p0 = part;
    double2* p1 = p0 + (size_t)BATCH * N0;
    double2* p2 = p1 + (size_t)BATCH * N1;
    double2* p3 = p2 + (size_t)BATCH * N2;

    // Co-resident grid size: 40960 B LDS -> 4 blocks/CU -> 1024 on 256 CUs.
    // Query occupancy to stay safe if regalloc shifts.
    static int NB = 0;
    if (NB <= 0) {
        int maxB = 0;
        if (hipOccupancyMaxActiveBlocksPerMultiprocessor(&maxB, mega_kernel, 256, 0)
                != hipSuccess || maxB < 1)
            maxB = 4;
        NB = maxB * 256;
        if (NB > (N0 + ND1) * BATCH) NB = (N0 + ND1) * BATCH;
    }

    MegaParams P;
    P.ref = ref;   P.dist = dist;  P.gw = gw;
    P.ref1 = ref1; P.dist1 = dist1;
    P.ref2 = ref2; P.dist2 = dist2;
    P.ref3 = ref3; P.dist3 = dist3;
    P.p0 = p0; P.p1 = p1; P.p2 = p2; P.p3 = p3;
    P.out = out;

    void* kargs[] = { &P };
    hipLaunchCooperativeKernel(mega_kernel, dim3(NB), dim3(256), kargs, 0, stream);
}

// Round 7
// 193.713 us; speedup vs baseline: 2.0722x; 2.0722x over previous
//
#include <hip/hip_runtime.h>
#include <math.h>

#define VIF_EPS       1e-10f
#define SIGMA_NSQ     2.0f
#define SIGMA_MAX_INV (4.0f / (255.0f * 255.0f))
#define GAIN_LIMIT    100.0f

typedef float v2f __attribute__((ext_vector_type(2)));
typedef float v4f __attribute__((ext_vector_type(4)));

static __device__ __forceinline__ v2f splat2(float s) {
    v2f v; v.x = s; v.y = s; return v;
}

// jnp.pad mode='reflect' (no edge duplication). Overshoot < dim, single reflection suffices.
__device__ __forceinline__ int reflect_idx(int i, int n) {
    i = (i < 0) ? -i : i;
    i = (i >= n) ? (2 * n - 2 - i) : i;
    return i;
}

// Reference: sigma=N/5; g=exp(-x^2/(2 sigma^2)); win=outer(g,g)/sum -> separable gn = g/sum(g).
// R9: computed once into workspace (same device float ops -> bit-identical weights).
template <int N>
__device__ __forceinline__ void fill_weights_global(float* gw) {
    const float sigma = (float)N / 5.0f;
    const float denom = 2.0f * sigma * sigma;
    float tmp[N];
    float s = 0.0f;
    for (int i = 0; i < N; ++i) {
        float x = (float)i - (float)(N - 1) * 0.5f;
        float g = expf(-(x * x) / denom);
        tmp[i] = g;
        s += g;
    }
    for (int i = 0; i < N; ++i) gw[i] = tmp[i] / s;
}

// K0: weight table + completion-counter reset (runs strictly before K4 every
// replay -> counter protocol is replay-safe).
__global__ __launch_bounds__(64) void init_weights_kernel(float* __restrict__ gw,
                                                          unsigned* __restrict__ counter) {
    const int tid = threadIdx.x;
    if (tid == 0) fill_weights_global<17>(gw + 0);
    else if (tid == 1) fill_weights_global<9>(gw + 17);
    else if (tid == 2) fill_weights_global<5>(gw + 26);
    else if (tid == 3) fill_weights_global<3>(gw + 31);
    else if (tid == 4) *counter = 0u;
}

// Weight buffer offsets per N.
__host__ __device__ constexpr int w_off(int N) {
    return (N == 17) ? 0 : (N == 9) ? 17 : (N == 5) ? 26 : 31;
}

// R7: 256-column tile (VC = blockDim = 256). Output tile width (multiple of 4).
// 1920 = 8*240 exact at level 0.
constexpr int tile_w(int N) { return (256 - (N - 1)) & ~3; }

// ---- static shared layouts ----
// R8: EXACT-FIT 40960 B = 4 blocks/CU in 160 KiB exactly.
template <int N>
struct alignas(16) StatsSmem {
    v2f   a[8][256];    // (conv r, conv d)           16384 B
    v2f   bq[8][256];   // (conv r^2, conv d^2)       16384 B
    float c[8][256];    // conv rd                     8192 B
};                      // total 40960 B exactly
// Down: vertical (r,d)-packed results for a 120x8 output tile.
template <int N>
struct alignas(16) DownSmem {
    v2f vb[8][252];
};

// ---------------- stats body (vertical-first separable VIF) ----------------
// bx flattened Y-MAJOR (ytile = bx % sy) for L2 reuse of vertical halos.
// R6: channel-pair packed fp32. R7: 1 column/thread phase 1; halo-minimum rows;
// u32 voffset + SGPR-base loads. R8: exact-fit LDS + rsum overlay. R9: weights
// from global. Per-output tap order preserved -> conv bit-identical.
template <int N>
__device__ __forceinline__ void stats_body(
    StatsSmem<N>& sm, const float* __restrict__ refp, const float* __restrict__ distp,
    const float* __restrict__ gw,
    int h, int w, float shift, double2* __restrict__ partial,
    int sy, int sx, int bx, int b) {
    constexpr int P   = (N - 1) / 2;
    constexpr int TW  = tile_w(N);
    constexpr int TH  = 8;
    constexpr int LR  = TH + 2 * P;      // rows loaded per column (halo minimum)
    constexpr int XG4 = TW / 4;          // 4-output x-groups per row
    constexpr int NT  = TH * XG4;        // phase-2 tasks (<= 504)
    constexpr int REPS = (NT + 255) / 256;

    const int tid = threadIdx.x;
    const int ytile = bx % sy;
    const int xtile = bx / sy;
    const int x0 = xtile * TW;
    const int y0 = ytile * TH;

    float wr[N];
#pragma unroll
    for (int j = 0; j < N; ++j) wr[j] = gw[j];   // uniform -> s_load, stays SGPR

    // ---- Phase 1: vertical conv from global (1 column/thread, 8 outputs) ----
    {
        const int cc = tid;                       // column 0..255
        const int gx = reflect_idx(x0 + cc - P, w);
        const float* rbase = refp  + (size_t)b * h * w;   // uniform -> SGPR base
        const float* dbase = distp + (size_t)b * h * w;

        v2f accA[TH], accB[TH];
        float accC[TH];
#pragma unroll
        for (int t = 0; t < TH; ++t) {
            accA[t] = splat2(0.f);
            accB[t] = splat2(0.f);
            accC[t] = 0.f;
        }

        auto acc_push = [&](int i, float r, float d) {
            v2f rd; rd.x = r; rd.y = d;
            v2f sq = rd * rd;          // v_pk_mul_f32: (r^2, d^2)
            float x = r * d;
#pragma unroll
            for (int t = 0; t < TH; ++t) {
                const int j = i - t;               // j-ascending per output t
                if (j >= 0 && j < N) {
                    const float wj = wr[j];
                    accA[t] += splat2(wj) * rd;    // v_pk_fma_f32
                    accB[t] += splat2(wj) * sq;
                    accC[t] += wj * x;
                }
            }
        };

        const int rowlo = y0 - P;
        if (rowlo >= 0 && rowlo + LR <= h) {
            // Interior fast path: shared 32-bit byte offset, uniform bases.
            unsigned voff = (unsigned)(rowlo * w + gx) * 4u;
            const unsigned vstep = (unsigned)w * 4u;
#pragma unroll
            for (int i = 0; i < LR; ++i) {
                float r = *(const float*)((const char*)rbase + voff) - shift;
                float d = *(const float*)((const char*)dbase + voff) - shift;
                voff += vstep;
                acc_push(i, r, d);
            }
        } else {
#pragma unroll
            for (int i = 0; i < LR; ++i) {
                const int gy = reflect_idx(rowlo + i, h);
                const size_t o = (size_t)gy * w + gx;
                float r = rbase[o] - shift;
                float d = dbase[o] - shift;
                acc_push(i, r, d);
            }
        }
#pragma unroll
        for (int t = 0; t < TH; ++t) {
            sm.a[t][cc]  = accA[t];   // ds_write_b64, compile-time row offsets
            sm.bq[t][cc] = accB[t];
            sm.c[t][cc]  = accC[t];
        }
    }
    __syncthreads();

    // ---- Phase 2: horizontal conv + VIF math (4 outputs/task, REPS task reps) ----
    float num_v = 0.f, den_v = 0.f;
    {
        constexpr int WC  = N + 3;         // window columns (even: N odd)
        constexpr int F4C = (WC + 3) / 4;
#pragma unroll
        for (int rep = 0; rep < REPS; ++rep) {
            const int task = tid + 256 * rep;
            if (task < NT) {
                const int row = task / XG4;
                const int xg  = task - row * XG4;

                v2f muA[4], muB[4];
                float muC[4];
#pragma unroll
                for (int q = 0; q < 4; ++q) {
                    muA[q] = splat2(0.f);
                    muB[q] = splat2(0.f);
                    muC[q] = 0.f;
                }

                const v4f* A4 = (const v4f*)&sm.a[row][xg * 4];
                const v4f* B4 = (const v4f*)&sm.bq[row][xg * 4];
#pragma unroll
                for (int f = 0; f < WC / 2; ++f) {
                    v4f ta = A4[f];
                    v4f tb = B4[f];
#pragma unroll
                    for (int hlf = 0; hlf < 2; ++hlf) {
                        const int k = 2 * f + hlf;
                        v2f pa = hlf ? __builtin_shufflevector(ta, ta, 2, 3)
                                     : __builtin_shufflevector(ta, ta, 0, 1);
                        v2f pb = hlf ? __builtin_shufflevector(tb, tb, 2, 3)
                                     : __builtin_shufflevector(tb, tb, 0, 1);
#pragma unroll
                        for (int q = 0; q < 4; ++q) {
                            const int j = k - q;  // j-ascending per output
                            if (j >= 0 && j < N) {
                                const float wj = wr[j];
                                muA[q] += splat2(wj) * pa;
                                muB[q] += splat2(wj) * pb;
                            }
                        }
                    }
                }
                // Scalar rd plane.
                {
                    const v4f* C4 = (const v4f*)&sm.c[row][xg * 4];
#pragma unroll
                    for (int f = 0; f < F4C; ++f) {
                        v4f t = C4[f];
#pragma unroll
                        for (int e = 0; e < 4; ++e) {
                            const int k = 4 * f + e;
                            const float x = (e == 0) ? t.x : (e == 1) ? t.y
                                          : (e == 2) ? t.z : t.w;
#pragma unroll
                            for (int q = 0; q < 4; ++q) {
                                const int j = k - q;
                                if (j >= 0 && j < N) muC[q] += wr[j] * x;
                            }
                        }
                    }
                }

                const int gy = y0 + row;
#pragma unroll
                for (int q = 0; q < 4; ++q) {
                    int gx = x0 + xg * 4 + q;
                    if (gx < w && gy < h) {
                        float mu1 = muA[q].x, mu2 = muA[q].y;
                        float s1  = fmaxf(0.f, muB[q].x - mu1 * mu1);
                        float s2  = fmaxf(0.f, muB[q].y - mu2 * mu2);
                        float s12 = muC[q] - mu1 * mu2;

                        float g  = s12 / (s1 + VIF_EPS);
                        float sv = s2 - g * s12;
                        if (s1 < VIF_EPS) { g = 0.f; sv = s2; s1 = 0.f; }
                        if (s2 < VIF_EPS) { g = 0.f; sv = 0.f; }
                        if (g  < 0.f)     { sv = s2; g = 0.f; }
                        if (sv <= VIF_EPS) sv = VIF_EPS;
                        g = fminf(g, GAIN_LIMIT);

                        float num_ar = __log2f(1.f + g * g * s1 / (sv + SIGMA_NSQ));
                        float den_ar = __log2f(1.f + s1 / SIGMA_NSQ);
                        if (s12 < 0.f) num_ar = 0.f;
                        if (s1 < SIGMA_NSQ) { num_ar = 1.f - s2 * SIGMA_MAX_INV; den_ar = 1.f; }
                        num_v += num_ar;
                        den_v += den_ar;
                    }
                }
            }
        }
    }

    // Block reduction. rsum overlaid on the a-plane.
#pragma unroll
    for (int off = 32; off > 0; off >>= 1) {
        num_v += __shfl_down(num_v, off);
        den_v += __shfl_down(den_v, off);
    }
    __syncthreads();                      // phase-2 LDS reads complete
    float* rs = reinterpret_cast<float*>(&sm);
    const int wid = tid >> 6, lane = tid & 63;
    if (lane == 0) { rs[wid] = num_v; rs[4 + wid] = den_v; }
    __syncthreads();
    if (tid == 0) {
        float ns = rs[0] + rs[1] + rs[2] + rs[3];
        float ds = rs[4] + rs[5] + rs[6] + rs[7];
        partial[(size_t)b * (sy * sx) + bx] = make_double2((double)ns, (double)ds);
    }
}

// ---------------- downsample body: vertical-first, 120x8 output tile ----------------
template <int N>
__device__ __forceinline__ void down_body(
    DownSmem<N>& sm, const float* __restrict__ rin, const float* __restrict__ din,
    const float* __restrict__ gw,
    float* __restrict__ rout, float* __restrict__ dout,
    int h, int w, int h2, int w2, float shift, int dgx, int bx, int b) {
    constexpr int P   = (N - 1) / 2;
    constexpr int TOW = 120, TOH = 8;
    constexpr int IC  = 2 * (TOW - 1) + N;   // input cols needed (<= 247)
    constexpr int NR  = 2 * (TOH - 1) + N;   // input rows needed (14+N)
    constexpr int XG4 = TOW / 4;             // 30 x-groups (4 outputs each)
    constexpr int WL  = N + 6;               // window v2f cols for 4 outputs

    float wr[N];
#pragma unroll
    for (int j = 0; j < N; ++j) wr[j] = gw[j];   // uniform -> s_load

    const int tid = threadIdx.x;
    const int xt  = bx % dgx;
    const int yt  = bx / dgx;
    const int x0  = xt * TOW;
    const int y0  = yt * TOH;

    // ---- Vertical decimating pass (packed, streaming) ----
    if (tid < IC) {
        const int gx = reflect_idx(2 * x0 - P + tid, w);
        const int rowlo = 2 * y0 - P;
        const float* rbase = rin + (size_t)b * h * w;
        const float* dbase = din + (size_t)b * h * w;

        v2f acc[TOH];
#pragma unroll
        for (int t = 0; t < TOH; ++t) acc[t] = splat2(0.f);

        const bool interior = (rowlo >= 0) && (rowlo + NR <= h);
        if (interior) {
            unsigned voff = (unsigned)(rowlo * w + gx) * 4u;
            const unsigned vstep = (unsigned)w * 4u;
#pragma unroll
            for (int i = 0; i < NR; ++i) {
                v2f x;
                x.x = *(const float*)((const char*)rbase + voff) - shift;
                x.y = *(const float*)((const char*)dbase + voff) - shift;
                voff += vstep;
#pragma unroll
                for (int t = 0; t < TOH; ++t) {
                    const int j = i - 2 * t;
                    if (j >= 0 && j < N) acc[t] += splat2(wr[j]) * x;
                }
            }
        } else {
#pragma unroll
            for (int i = 0; i < NR; ++i) {
                const int gy = reflect_idx(rowlo + i, h);
                const size_t o = (size_t)gy * w + gx;
                v2f x; x.x = rbase[o] - shift; x.y = dbase[o] - shift;
#pragma unroll
                for (int t = 0; t < TOH; ++t) {
                    const int j = i - 2 * t;
                    if (j >= 0 && j < N) acc[t] += splat2(wr[j]) * x;
                }
            }
        }
#pragma unroll
        for (int t = 0; t < TOH; ++t) sm.vb[t][tid] = acc[t];   // ds_write_b64
    }
    __syncthreads();

    // ---- Horizontal decimating pass (packed) ----
    if (tid < TOH * XG4) {   // 240 threads
        const int row = tid / XG4;
        const int xg  = tid - row * XG4;

        v2f o[4];
#pragma unroll
        for (int q = 0; q < 4; ++q) o[q] = splat2(0.f);

        const v4f* s4 = (const v4f*)&sm.vb[row][8 * xg];
#pragma unroll
        for (int f = 0; f < (WL + 1) / 2; ++f) {
            v4f t = s4[f];
#pragma unroll
            for (int hlf = 0; hlf < 2; ++hlf) {
                const int k = 2 * f + hlf;
                v2f p = hlf ? __builtin_shufflevector(t, t, 2, 3)
                            : __builtin_shufflevector(t, t, 0, 1);
#pragma unroll
                for (int q = 0; q < 4; ++q) {
                    const int j = k - 2 * q;   // j-ascending per output: bit-identical
                    if (j >= 0 && j < N) o[q] += splat2(wr[j]) * p;
                }
            }
        }
        const int gy = y0 + row;
        if (gy < h2) {
            float* rp = rout + (size_t)b * h2 * w2 + (size_t)gy * w2 + x0 + 4 * xg;
            float* dp = dout + (size_t)b * h2 * w2 + (size_t)gy * w2 + x0 + 4 * xg;
            *(float4*)rp = make_float4(o[0].x, o[1].x, o[2].x, o[3].x);
            *(float4*)dp = make_float4(o[0].y, o[1].y, o[2].y, o[3].y);
        }
    }
}

// ---------------- fused kernels (static union LDS; grid split by blockIdx.x) ----------------
template <int NS, int ND>
__global__ __launch_bounds__(256) void fused_kernel(
    const float* __restrict__ sref, const float* __restrict__ sdist,
    const float* __restrict__ gw,
    int sh, int sw, float sshift, double2* __restrict__ partial, int sy, int sx,
    float* __restrict__ drout, float* __restrict__ ddout,
    int dh2, int dw2, int dgx, int nStats) {
    __shared__ union {
        StatsSmem<NS> s;
        DownSmem<ND>  d;
    } u;
    const int bx = blockIdx.x;
    const int b  = blockIdx.z;
    if (bx < nStats)
        stats_body<NS>(u.s, sref, sdist, gw + w_off(NS), sh, sw, sshift,
                       partial, sy, sx, bx, b);
    else
        down_body<ND>(u.d, sref, sdist, gw + w_off(ND), drout, ddout,
                      sh, sw, dh2, dw2, sshift, dgx, bx - nStats, b);
}

// ---------------- K4: stats<3> + last-block-done final reduce ----------------
// R11: each block writes its partial, then __threadfence + atomicAdd(counter).
// The LAST finisher performs the identical 16-(b,s) double reduction that the
// old reduce_kernel did (same stride-256 / shfl-tree / 4-way grouping ->
// bit-identical output). Counter is zeroed by K0 each replay (K0 strictly
// precedes K4 in launch order), so no replay-state hazard.
template <int N>
__global__ __launch_bounds__(256) void stats_reduce_kernel(
    const float* __restrict__ refp, const float* __restrict__ distp,
    const float* __restrict__ gw,
    int h, int w, float shift, double2* __restrict__ partial, int sy, int sx,
    unsigned* __restrict__ counter,
    const double2* __restrict__ part, float* __restrict__ out,
    int4 bases, int4 counts) {
    __shared__ StatsSmem<N> sm;
    __shared__ unsigned slast;
    __shared__ double sn[4], sd[4];

    stats_body<N>(sm, refp, distp, gw + w_off(N), h, w, shift, partial,
                  sy, sx, blockIdx.x, blockIdx.z);

    // Completion protocol (producer side): partial store -> fence -> count.
    __threadfence();
    if (threadIdx.x == 0) {
        const unsigned total = gridDim.x * gridDim.z;
        unsigned old = atomicAdd(counter, 1u);
        slast = (old == total - 1u) ? 1u : 0u;
    }
    __syncthreads();
    if (!slast) return;

    // Consumer side: all other blocks' fenced stores are visible.
    __threadfence();
    const int tid = threadIdx.x;
    for (int v = 0; v < 16; ++v) {
        const int s = v & 3;
        const int b = v >> 2;
        const int base = (&bases.x)[s];
        const int cnt  = (&counts.x)[s];
        const double2* p = part + base + (size_t)b * cnt;

        double ns = 0.0, ds = 0.0;
        for (int i = tid; i < cnt; i += 256) {
            double2 t = p[i];
            ns += t.x;
            ds += t.y;
        }
#pragma unroll
        for (int off = 32; off > 0; off >>= 1) {
            ns += __shfl_down(ns, off);
            ds += __shfl_down(ds, off);
        }
        const int wid = tid >> 6, lane = tid & 63;
        if (lane == 0) { sn[wid] = ns; sd[wid] = ds; }
        __syncthreads();
        if (tid == 0) {
            double Nv = sn[0] + sn[1] + sn[2] + sn[3];
            double Dv = sd[0] + sd[1] + sd[2] + sd[3];
            out[b * 4 + s] = (float)(Nv / Dv);
        }
        __syncthreads();   // protect sn/sd reuse across pairs
    }
}

extern "C" void kernel_launch(void* const* d_in, const int* in_sizes, int n_in,
                              void* d_out, int out_size, void* d_ws, size_t ws_size,
                              hipStream_t stream) {
    const float* ref  = (const float*)d_in[0];
    const float* dist = (const float*)d_in[1];
    float* out = (float*)d_out;

    const int B = 4;
    const int H0 = 1080, W0 = 1920;
    const int H1 = 540,  W1 = 960;
    const int H2 = 270,  W2 = 480;
    const int H3 = 135,  W3 = 240;

    char*  ws  = (char*)d_ws;
    size_t off = 0;
    auto alloc = [&](size_t bytes) -> void* {
        void* p = ws + off;
        off += (bytes + 255) & ~(size_t)255;
        return p;
    };
    float*    gw      = (float*)alloc(34 * sizeof(float));   // weight table (17+9+5+3)
    unsigned* counter = (unsigned*)alloc(sizeof(unsigned));  // K4 completion counter
    float* ref1  = (float*)alloc((size_t)B * H1 * W1 * 4);
    float* dist1 = (float*)alloc((size_t)B * H1 * W1 * 4);
    float* ref2  = (float*)alloc((size_t)B * H2 * W2 * 4);
    float* dist2 = (float*)alloc((size_t)B * H2 * W2 * 4);
    float* ref3  = (float*)alloc((size_t)B * H3 * W3 * 4);
    float* dist3 = (float*)alloc((size_t)B * H3 * W3 * 4);

    // Stats grids (tile = tile_w(N) x 8), flattened y-major.
    // tile_w: 17->240 (1920 = 8*240 exact), 9->248, 5->252, 3->252.
    const int sx0 = (W0 + tile_w(17) - 1) / tile_w(17), sy0 = (H0 + 7) / 8;
    const int sx1 = (W1 + tile_w(9)  - 1) / tile_w(9),  sy1 = (H1 + 7) / 8;
    const int sx2 = (W2 + tile_w(5)  - 1) / tile_w(5),  sy2 = (H2 + 7) / 8;
    const int sx3 = (W3 + tile_w(3)  - 1) / tile_w(3),  sy3 = (H3 + 7) / 8;
    const int n0 = sx0 * sy0, n1 = sx1 * sy1, n2 = sx2 * sy2, n3 = sx3 * sy3;

    // Down grids: 120x8 output tiles (W1/W2/W3 are exact multiples of 120).
    const int dgx1 = W1 / 120, nD1 = dgx1 * ((H1 + 7) / 8);
    const int dgx2 = W2 / 120, nD2 = dgx2 * ((H2 + 7) / 8);
    const int dgx3 = W3 / 120, nD3 = dgx3 * ((H3 + 7) / 8);

    double2* part = (double2*)alloc((size_t)B * (n0 + n1 + n2 + n3) * sizeof(double2));
    double2* p0 = part;
    double2* p1 = p0 + (size_t)B * n0;
    double2* p2 = p1 + (size_t)B * n1;
    double2* p3 = p2 + (size_t)B * n2;

    dim3 blk(256);

    // K0: weight table + counter reset (once per replay).
    init_weights_kernel<<<1, 64, 0, stream>>>(gw, counter);

    // K1: stats<17>(level0) + down<9>(level0 -> level1)
    fused_kernel<17, 9><<<dim3(n0 + nD1, 1, B), blk, 0, stream>>>(
        ref, dist, gw, H0, W0, 128.0f, p0, sy0, sx0,
        ref1, dist1, H1, W1, dgx1, n0);

    // K2: stats<9>(level1) + down<5>(level1 -> level2)
    fused_kernel<9, 5><<<dim3(n1 + nD2, 1, B), blk, 0, stream>>>(
        ref1, dist1, gw, H1, W1, 0.0f, p1, sy1, sx1,
        ref2, dist2, H2, W2, dgx2, n1);

    // K3: stats<5>(level2) + down<3>(level2 -> level3)
    fused_kernel<5, 3><<<dim3(n2 + nD3, 1, B), blk, 0, stream>>>(
        ref2, dist2, gw, H2, W2, 0.0f, p2, sy2, sx2,
        ref3, dist3, H3, W3, dgx3, n2);

    // K4: stats<3>(level3) + fused last-block final reduce (replaces old K5).
    stats_reduce_kernel<3><<<dim3(n3, 1, B), blk, 0, stream>>>(
        ref3, dist3, gw, H3, W3, 0.0f, p3, sy3, sx3,
        counter, part, out,
        make_int4(0, B * n0, B * (n0 + n1), B * (n0 + n1 + n2)),
        make_int4(n0, n1, n2, n3));
}